// Round 3
// baseline (374.598 us; speedup 1.0000x reference)
//
#include <hip/hip_runtime.h>
#include <math.h>

// Problem constants (fixed by reference): B=1024, NMAX=128, D=256, NUM=4
#define BB   1024
#define DD   256
#define LOGD 5.5451774444795624753f   // log(256)

typedef __attribute__((ext_vector_type(8))) short short8;   // 8 bf16 = 4 VGPRs
typedef __attribute__((ext_vector_type(4))) float f32x4;    // MFMA acc

__device__ __forceinline__ float wave_sum(float v){
  #pragma unroll
  for (int off=32; off>0; off>>=1) v += __shfl_xor(v, off, 64);
  return v;
}
__device__ __forceinline__ float wave_max(float v){
  #pragma unroll
  for (int off=32; off>0; off>>=1) v = fmaxf(v, __shfl_xor(v, off, 64));
  return v;
}
__device__ __forceinline__ float fast_tanh(float x){
  return 1.0f - 2.0f/(__expf(2.0f*x)+1.0f);
}
__device__ __forceinline__ unsigned short f2bf(float f){
  unsigned int u = __float_as_uint(f);
  unsigned int r = u + 0x7FFFu + ((u >> 16) & 1u);   // RNE
  return (unsigned short)(r >> 16);
}
// uniform value -> SGPR (validity: input must be wave-uniform)
__device__ __forceinline__ float rfl(float x){
  return __uint_as_float(__builtin_amdgcn_readfirstlane(__float_as_uint(x)));
}
// s16 codec for log-domain A state: values provably in (-64, ~0]; scale 512
// -> abs err 1e-3 uniformly (round-nearest via trunc(v*512-0.5) for v<=0).
__device__ __forceinline__ int encq(float v){
  return (int)(fmaxf(v, -63.0f)*512.0f - 0.5f);
}
__device__ __forceinline__ float decq(int q16){
  return (float)q16 * (1.0f/512.0f);
}
// s16 codec for dual z: |z| <= sum(r_k) ~ 3 < 8; scale 4096 -> abs err 1.2e-4.
// RNE via the 1.5*2^23 magic-add trick (2 VALU ops, exact for |z*4096|<2^22).
__device__ __forceinline__ int zenc(float z){
  float t = fmaf(z, 4096.0f, 12582912.0f);   // 12582912 = 0x4B400000
  return __float_as_int(t) - 0x4B400000;
}
__device__ __forceinline__ float zdec(int q){
  return (float)q * (1.0f/4096.0f);
}
__device__ __forceinline__ int upk16(unsigned v, int hi){
  return hi ? ((int)v >> 16) : (((int)(v << 16)) >> 16);
}

// ---- K_pre: fused prologue (castW + bounds + params), one launch ----
// blocks 0..63: W1 fp32->bf16 cast; blocks 64..68: segment bounds; block 69: params.
__global__ void k_pre(const float* __restrict__ W1, unsigned short* __restrict__ w1b,
                      const int* __restrict__ batch, int T, int* __restrict__ starts,
                      const float* __restrict__ rho, const float* __restrict__ a1,
                      const float* __restrict__ a2, const float* __restrict__ a3,
                      float* __restrict__ P)
{
  const int blk = blockIdx.x, tid = threadIdx.x;
  if (blk < 64){
    const int t = blk*256 + tid;
    #pragma unroll
    for (int i=0;i<2;i++){
      const int idx = (t*2 + i)*4;
      const float4 v = *(const float4*)(W1 + idx);
      *(ushort4*)(w1b + idx) = make_ushort4(f2bf(v.x), f2bf(v.y), f2bf(v.z), f2bf(v.w));
    }
  } else if (blk < 69){
    const int b = (blk-64)*256 + tid;
    if (b <= BB){
      int lo = 0, hi = T;
      while (lo < hi){ int mid = (lo+hi)>>1; if (batch[mid] < b) lo = mid+1; else hi = mid; }
      starts[b] = lo;
    }
  } else if (tid == 0){
    // P: [0..3]=r [4..7]=1/(b1+r) [8..11]=1/(b2+r) [12..15]=log_mu@k [16..19]=b3 [20..23]=1/(b3+r)
    float lm = -LOGD, z1 = 0.f;
    for (int k=0;k<4;k++){
      float r  = log1pf(expf(rho[k]));
      float b1 = log1pf(expf(a1[k]));
      float b2 = log1pf(expf(a2[k]));
      float b3 = log1pf(expf(a3[k]));
      P[k]    = r;
      P[4+k]  = 1.f/(b1+r);
      P[8+k]  = 1.f/(b2+r);
      P[12+k] = lm;              // mu used by S-update of iteration k
      P[16+k] = b3;
      P[20+k] = 1.f/(b3+r);
      float lmn = (b3*(-LOGD) - z1 + r*lm)/(b3+r);
      z1 += r*(expf(lmn)-expf(lm));
      lm = lmn;
    }
  }
}

// ---- K2: fused MLP via bf16 MFMA (unchanged structure) ----
#define LPW 72
__global__ __launch_bounds__(512, 2) void k_mlp(
    const float* __restrict__ x, const unsigned short* __restrict__ w1b,
    const float* __restrict__ W2, float* __restrict__ logits, int T)
{
  __shared__ unsigned short Xs[128*LPW];   // 18432 B
  __shared__ unsigned short Ws[128*LPW];   // 18432 B
  __shared__ float lred[128];
  const int by = blockIdx.x;   // hidden quarter 0..3
  const int bx = blockIdx.y;   // row tile
  const int tid = threadIdx.x;
  if (tid < 128) lred[tid] = 0.f;

  const int l = tid & 63;
  const int w = tid >> 6;             // wave 0..7
  const int wm = w >> 2;              // M half (0..1)
  const int wn = w & 3;               // N quarter (0..3)
  const int lr = l & 15, quad = l >> 4;
  const int srow = tid >> 2;          // x-staging row 0..127
  const int sseg = tid & 3;           // 16-float segment of BK=64
  const int wrow = tid >> 3;          // w-staging row 0..63 (x2 halves)
  const int wseg = tid & 7;           // 8-short chunk

  f32x4 acc[4][2];
  #pragma unroll
  for (int mi=0;mi<4;mi++)
    #pragma unroll
    for (int ni=0;ni<2;ni++) acc[mi][ni] = (f32x4){0.f,0.f,0.f,0.f};

  for (int kt=0; kt<4; kt++){
    const int k0 = kt*64;
    {
      const int grow = bx*128 + srow;
      #pragma unroll
      for (int i=0;i<4;i++){
        float4 v = make_float4(0.f,0.f,0.f,0.f);
        if (grow < T) v = *(const float4*)(x + (size_t)grow*DD + k0 + sseg*16 + i*4);
        *(ushort4*)&Xs[srow*LPW + sseg*16 + i*4] =
            make_ushort4(f2bf(v.x), f2bf(v.y), f2bf(v.z), f2bf(v.w));
      }
    }
    #pragma unroll
    for (int h=0; h<2; h++){
      const int r = h*64 + wrow;
      *(short8*)&Ws[r*LPW + wseg*8] =
          *(const short8*)(w1b + (size_t)(by*128 + r)*DD + k0 + wseg*8);
    }
    __syncthreads();
    #pragma unroll
    for (int ks=0; ks<2; ks++){
      short8 afr[4], bfr[2];
      #pragma unroll
      for (int mi=0;mi<4;mi++)
        afr[mi] = *(const short8*)&Xs[(wm*64 + mi*16 + lr)*LPW + ks*32 + quad*8];
      #pragma unroll
      for (int ni=0;ni<2;ni++)
        bfr[ni] = *(const short8*)&Ws[(wn*32 + ni*16 + lr)*LPW + ks*32 + quad*8];
      #pragma unroll
      for (int mi=0;mi<4;mi++)
        #pragma unroll
        for (int ni=0;ni<2;ni++)
          acc[mi][ni] = __builtin_amdgcn_mfma_f32_16x16x32_bf16(afr[mi], bfr[ni], acc[mi][ni], 0, 0, 0);
    }
    __syncthreads();
  }

  float w2v[2];
  #pragma unroll
  for (int ni=0;ni<2;ni++) w2v[ni] = W2[by*128 + wn*32 + ni*16 + lr];
  #pragma unroll
  for (int mi=0;mi<4;mi++){
    float p[4];
    #pragma unroll
    for (int v=0; v<4; v++){
      p[v] = fast_tanh(acc[mi][0][v])*w2v[0] + fast_tanh(acc[mi][1][v])*w2v[1];
      #pragma unroll
      for (int off=1; off<16; off<<=1) p[v] += __shfl_xor(p[v], off, 64);
    }
    if (lr == 0){
      #pragma unroll
      for (int v=0; v<4; v++)
        atomicAdd(&lred[wm*64 + mi*16 + quad*4 + v], p[v]);
    }
  }
  __syncthreads();
  if (tid < 128){
    const int grow = bx*128 + tid;
    if (grow < T) atomicAdd(logits + grow, lred[tid]);
  }
}

// ---- K4: BADMM solver ----
// Round 1-2 post-mortem: with 1024-thread blocks, 2 blocks/CU needs 8 waves/EU
// -> 64-VGPR cap -> allocator SPILLS (VGPR_Count 32, scratch FETCH/WRITE) and
// the occupancy win is cancelled (143us vs 135us baseline). Dead end.
// Round 3: 512-thread blocks (8 waves), each wave owns 16 rows.
//  * 2 blocks/CU now only needs 4 waves/EU -> 128-VGPR cap. Demand ~100
//    (zp[16]=32 persistent + transients + any uniform values the compiler
//    keeps in VGPRs) -> fits, NO spill.
//  * Same 1024 resident lanes/CU as baseline, but the per-sweep barriers +
//    serial colsum + tail of one block are covered by the OTHER block.
//  * colv separate again (73 KB total: As 64K + red 8K + colv 1K; 2x73=146K
//    fits 160K) -> back to 2 barriers/sweep instead of 3.
//  * lane->column map changed from l+64j to 4l+j: the 4 x-loads per row
//    become ONE global_load_dwordx4 (4x fewer VMEM instrs). A-state layout
//    [row][4l+j] unchanged (was already lane-contiguous packs); red/colv
//    stay conflict-free (b128 stride-4-bank pattern / stride-1).
__global__ __launch_bounds__(512, 4) void k_solver(
    const float* __restrict__ x, const float* __restrict__ logits,
    const int* __restrict__ starts, const float* __restrict__ P,
    float* __restrict__ out)
{
  __shared__ __align__(16) unsigned short As[128*DD]; // 64 KB: s16 log_t state
  __shared__ float red[8*DD];                         // 8 KB: col partials
  __shared__ float colv[DD];                          // 1 KB: column log-sum
  const int b = blockIdx.x;
  const int start = starts[b];
  const int len = starts[b+1] - start;
  const int tid = threadIdx.x;
  const int w = tid >> 6, l = tid & 63;
  const int n0 = w*16;
  int nv = len - n0; nv = nv < 0 ? 0 : (nv > 16 ? 16 : nv);

  // scalar params (wave-uniform s_loads)
  const float r0=P[0], r1=P[1], r2=P[2], r3=P[3];
  const float i10=P[4], i11=P[5], i12=P[6];
  const float i20=P[8], i21=P[9], i22=P[10], i23=P[11];
  const float mu0=P[12], mu1=P[13], mu2=P[14];
  const float b30=P[16], b31=P[17], b32=P[18];
  const float e30=P[20], e31=P[21], e32=P[22];

  // ---- fused segment softmax (per-wave redundant) ----
  const float* lg = logits + start;
  float v0 = (l      < len) ? lg[l]    : -3.0e38f;
  float v1 = (l+64   < len) ? lg[l+64] : -3.0e38f;
  float sm = wave_max(fmaxf(v0,v1));
  float se0 = (l    < len) ? __expf(v0-sm) : 0.f;
  float se1 = (l+64 < len) ? __expf(v1-sm) : 0.f;
  float ssum = wave_sum(se0+se1);
  const float sinv = 1.f/(ssum + 1e-16f);
  const float esel = (n0 < 64) ? se0 : se1;   // wave-uniform selector (16 | 64)

  // per-row state: wave-uniform -> SGPRs via readfirstlane
  float slq[16], eta[16], z2[16];
  uint2 zp[16];                                // packed s16 dual z (32 VGPRs)
  #pragma unroll
  for (int r=0;r<16;r++){
    const float ev = __shfl(esel, (n0+r)&63, 64);
    const float lqv = __logf(ev*sinv + 1e-8f);
    slq[r] = rfl(lqv);
    eta[r] = slq[r];
    z2[r]  = 0.f;
    zp[r].x = 0u; zp[r].y = 0u;
  }
  const int abase = (n0 << 8) + (l << 2);   // ushort index of this thread's 4-pack, row n0

  // ---- sweep 0: T-update(k=0) from registers + colsum for S(0) ----
  {
    float sp[4] = {0.f,0.f,0.f,0.f};
    #pragma unroll
    for (int r=0;r<16;r++){
      if (r < nv){
        const float4 xv4 = *(const float4*)(x + (size_t)(start+n0+r)*DD + 4*l);
        const float xv[4] = {xv4.x, xv4.y, xv4.z, xv4.w};
        const float a0 = slq[r] - LOGD;        // initial log_s (uniform per row)
        float y[4], se = 0.f;
        #pragma unroll
        for (int j=0;j<4;j++){ y[j] = (xv[j] + r0*a0) * i20; se += __expf(y[j]); }
        se = wave_sum(se);
        const float off = eta[r] - __logf(se);
        int q[4];
        #pragma unroll
        for (int j=0;j<4;j++) q[j] = encq(off + y[j]);
        uint2 pk;
        pk.x = ((unsigned)q[0] & 0xffffu) | ((unsigned)q[1] << 16);
        pk.y = ((unsigned)q[2] & 0xffffu) | ((unsigned)q[3] << 16);
        *(uint2*)&As[abase + (r<<8)] = pk;
        #pragma unroll
        for (int j=0;j<4;j++) sp[j] += __expf((r0*decq(q[j])) * i10);   // z=0
        // eta advance k=0 (uniform math -> keep in SGPR)
        const float en = (b30*slq[r] - z2[r] + r0*eta[r]) * e30;
        const float z2n = z2[r] + r0*(__expf(en) - __expf(eta[r]));
        z2[r] = rfl(z2n);
        eta[r] = rfl(en);
      }
    }
    #pragma unroll
    for (int j=0;j<4;j++) red[w*DD + 4*l + j] = sp[j];
  }
  __syncthreads();
  if (tid < DD){
    float s = 0.f;
    #pragma unroll
    for (int ww=0; ww<8; ww++) s += red[ww*DD + tid];
    colv[tid] = __logf(s);
  }
  __syncthreads();

  // ---- sweeps 1..2: S(k-1) + z-update + T(k) + colsum(k) ----
  #pragma unroll
  for (int k=1;k<3;k++){
    const float rkm = (k==1)? r0 : r1;
    const float ib1m= (k==1)? i10 : i11;
    const float mum = (k==1)? mu0 : mu1;
    const float rk  = (k==1)? r1 : r2;
    const float ib1k= (k==1)? i11 : i12;
    const float ib2k= (k==1)? i21 : i22;
    const float b3k = (k==1)? b31 : b32;
    const float e3k = (k==1)? e31 : e32;
    float lsc[4];
    #pragma unroll
    for (int j=0;j<4;j++) lsc[j] = colv[4*l + j];
    float sp[4] = {0.f,0.f,0.f,0.f};
    #pragma unroll
    for (int r=0;r<16;r++){
      if (r < nv){
        const float4 xv4 = *(const float4*)(x + (size_t)(start+n0+r)*DD + 4*l);
        const float xv[4] = {xv4.x, xv4.y, xv4.z, xv4.w};
        const uint2 pk = *(const uint2*)&As[abase + (r<<8)];
        const uint2 zr = zp[r];
        float y[4], se = 0.f;
        int nq[4];
        #pragma unroll
        for (int j=0;j<4;j++){
          const int q16 = upk16((j<2)? pk.x : pk.y, j&1);
          const float lt  = decq(q16);
          float zf = zdec(upk16((j<2)? zr.x : zr.y, j&1));
          const float ys  = (zf + rkm*lt) * ib1m;
          const float lsn = mum + ys - lsc[j];
          zf += rkm*(__expf(lt) - __expf(lsn));
          nq[j] = zenc(zf);
          y[j] = (xv[j] - zdec(nq[j]) + rk*lsn) * ib2k;
          se += __expf(y[j]);
        }
        zp[r].x = ((unsigned)nq[0] & 0xffffu) | ((unsigned)nq[1] << 16);
        zp[r].y = ((unsigned)nq[2] & 0xffffu) | ((unsigned)nq[3] << 16);
        se = wave_sum(se);
        const float off = eta[r] - __logf(se);
        int q[4];
        #pragma unroll
        for (int j=0;j<4;j++) q[j] = encq(off + y[j]);
        uint2 npk;
        npk.x = ((unsigned)q[0] & 0xffffu) | ((unsigned)q[1] << 16);
        npk.y = ((unsigned)q[2] & 0xffffu) | ((unsigned)q[3] << 16);
        *(uint2*)&As[abase + (r<<8)] = npk;
        #pragma unroll
        for (int j=0;j<4;j++) sp[j] += __expf((zdec(nq[j]) + rk*decq(q[j])) * ib1k);
        const float en = (b3k*slq[r] - z2[r] + rk*eta[r]) * e3k;
        const float z2n = z2[r] + rk*(__expf(en) - __expf(eta[r]));
        z2[r] = rfl(z2n);
        eta[r] = rfl(en);
      }
    }
    #pragma unroll
    for (int j=0;j<4;j++) red[w*DD + 4*l + j] = sp[j];
    __syncthreads();
    if (tid < DD){
      float s = 0.f;
      #pragma unroll
      for (int ww=0; ww<8; ww++) s += red[ww*DD + tid];
      colv[tid] = __logf(s);
    }
    __syncthreads();
  }

  // ---- sweep 3: S(2) + z-update + T(3) + output ----
  {
    float lsc[4];
    #pragma unroll
    for (int j=0;j<4;j++) lsc[j] = colv[4*l + j];
    float op[4] = {0.f,0.f,0.f,0.f};
    #pragma unroll
    for (int r=0;r<16;r++){
      if (r < nv){
        const float4 xv4 = *(const float4*)(x + (size_t)(start+n0+r)*DD + 4*l);
        const float xv[4] = {xv4.x, xv4.y, xv4.z, xv4.w};
        const uint2 pk = *(const uint2*)&As[abase + (r<<8)];
        const uint2 zr = zp[r];
        float ey[4], se = 0.f;
        #pragma unroll
        for (int j=0;j<4;j++){
          const int q16 = upk16((j<2)? pk.x : pk.y, j&1);
          const float lt  = decq(q16);
          float zf = zdec(upk16((j<2)? zr.x : zr.y, j&1));
          const float ys  = (zf + r2*lt) * i12;
          const float lsn = mu2 + ys - lsc[j];
          zf += r2*(__expf(lt) - __expf(lsn));
          const float yv = (xv[j] - zf + r3*lsn) * i23;
          ey[j] = __expf(yv);
          se += ey[j];
        }
        se = wave_sum(se);
        const float rs = __expf(eta[r]) / se;   // t = ey * exp(eta3)/se
        #pragma unroll
        for (int j=0;j<4;j++) op[j] += xv[j]*ey[j]*rs;
      }
    }
    #pragma unroll
    for (int j=0;j<4;j++) red[w*DD + 4*l + j] = op[j];
    __syncthreads();
    if (tid < DD){
      float s = 0.f;
      #pragma unroll
      for (int ww=0; ww<8; ww++) s += red[ww*DD + tid];
      out[(size_t)b*DD + tid] = 256.0f * s;
    }
  }
}

extern "C" void kernel_launch(void* const* d_in, const int* in_sizes, int n_in,
                              void* d_out, int out_size, void* d_ws, size_t ws_size,
                              hipStream_t stream) {
  const float* x    = (const float*)d_in[0];
  const int*   batch= (const int*)d_in[1];
  const float* W1   = (const float*)d_in[2];
  const float* W2   = (const float*)d_in[3];
  const float* rho  = (const float*)d_in[4];
  const float* a1   = (const float*)d_in[5];
  const float* a2   = (const float*)d_in[6];
  const float* a3   = (const float*)d_in[7];
  float* out = (float*)d_out;
  const int T = in_sizes[1];   // total ragged rows

  float* logits = (float*)d_ws;              // T floats
  int*   starts = (int*)(logits + T);        // B+1 ints (padded to 1028)
  float* P      = (float*)(starts + 1028);   // 24 floats (padded to 32)
  unsigned short* w1b = (unsigned short*)(P + 32);  // 512*256 bf16

  k_pre<<<70, 256, 0, stream>>>(W1, w1b, batch, T, starts, rho, a1, a2, a3, P);
  hipMemsetAsync(logits, 0, (size_t)T*sizeof(float), stream);
  k_mlp<<<dim3(4, (T+127)/128), 512, 0, stream>>>(x, w1b, W2, logits, T);
  k_solver<<<BB, 512, 0, stream>>>(x, logits, starts, P, out);
}

// Round 4
// 352.432 us; speedup vs baseline: 1.0629x; 1.0629x over previous
//
#include <hip/hip_runtime.h>
#include <math.h>

// Problem constants (fixed by reference): B=1024, NMAX=128, D=256, NUM=4
#define BB   1024
#define DD   256
#define LOGD 5.5451774444795624753f   // log(256)
#define RST  260                      // red row stride (floats): 260=4 mod 32 -> uniform banks

typedef __attribute__((ext_vector_type(8))) short short8;   // 8 bf16 = 4 VGPRs
typedef __attribute__((ext_vector_type(4))) float f32x4;    // MFMA acc

__device__ __forceinline__ float wave_sum(float v){
  #pragma unroll
  for (int off=32; off>0; off>>=1) v += __shfl_xor(v, off, 64);
  return v;
}
__device__ __forceinline__ float wave_max(float v){
  #pragma unroll
  for (int off=32; off>0; off>>=1) v = fmaxf(v, __shfl_xor(v, off, 64));
  return v;
}
// 16-lane-group sum: reduces 4 rows of a wave simultaneously (4-step chain)
__device__ __forceinline__ float grp_sum(float v){
  v += __shfl_xor(v, 1, 64);
  v += __shfl_xor(v, 2, 64);
  v += __shfl_xor(v, 4, 64);
  v += __shfl_xor(v, 8, 64);
  return v;
}
__device__ __forceinline__ float fast_tanh(float x){
  return 1.0f - 2.0f/(__expf(2.0f*x)+1.0f);
}
__device__ __forceinline__ unsigned short f2bf(float f){
  unsigned int u = __float_as_uint(f);
  unsigned int r = u + 0x7FFFu + ((u >> 16) & 1u);   // RNE
  return (unsigned short)(r >> 16);
}
// s16 codecs. A/log-state at scale 512 (abs err ~1e-3, range (-64,+16)).
// z at scale 4096 (|z| <= sum r_k ~ 3, abs err 1.2e-4).
__device__ __forceinline__ float decq(int q16){ return (float)q16 * (1.0f/512.0f); }
__device__ __forceinline__ int   zenc(float z){
  float t = fmaf(z, 4096.0f, 12582912.0f);   // RNE via 1.5*2^23 magic add
  return __float_as_int(t) - 0x4B400000;
}
__device__ __forceinline__ float zdec(int q){ return (float)q * (1.0f/4096.0f); }
__device__ __forceinline__ int lo16(unsigned u){ return ((int)(u<<16))>>16; }
__device__ __forceinline__ int hi16(unsigned u){ return ((int)u)>>16; }
__device__ __forceinline__ unsigned pk2(int a, int b){
  return ((unsigned)a & 0xffffu) | ((unsigned)b << 16);
}
// packed saturating s16 add: lt = sat(y_s16 + off_s16); sat(-32768)=-64.0 (==0 mass)
__device__ __forceinline__ unsigned pkadd_sat(unsigned a, unsigned b){
  unsigned d; asm("v_pk_add_i16 %0, %1, %2 clamp" : "=v"(d) : "v"(a), "v"(b)); return d;
}

// ---- K_pre: fused prologue (castW + bounds + params), one launch ----
__global__ void k_pre(const float* __restrict__ W1, unsigned short* __restrict__ w1b,
                      const int* __restrict__ batch, int T, int* __restrict__ starts,
                      const float* __restrict__ rho, const float* __restrict__ a1,
                      const float* __restrict__ a2, const float* __restrict__ a3,
                      float* __restrict__ P)
{
  const int blk = blockIdx.x, tid = threadIdx.x;
  if (blk < 64){
    const int t = blk*256 + tid;
    #pragma unroll
    for (int i=0;i<2;i++){
      const int idx = (t*2 + i)*4;
      const float4 v = *(const float4*)(W1 + idx);
      *(ushort4*)(w1b + idx) = make_ushort4(f2bf(v.x), f2bf(v.y), f2bf(v.z), f2bf(v.w));
    }
  } else if (blk < 69){
    const int b = (blk-64)*256 + tid;
    if (b <= BB){
      int lo = 0, hi = T;
      while (lo < hi){ int mid = (lo+hi)>>1; if (batch[mid] < b) lo = mid+1; else hi = mid; }
      starts[b] = lo;
    }
  } else if (tid == 0){
    float lm = -LOGD, z1 = 0.f;
    for (int k=0;k<4;k++){
      float r  = log1pf(expf(rho[k]));
      float b1 = log1pf(expf(a1[k]));
      float b2 = log1pf(expf(a2[k]));
      float b3 = log1pf(expf(a3[k]));
      P[k]    = r;
      P[4+k]  = 1.f/(b1+r);
      P[8+k]  = 1.f/(b2+r);
      P[12+k] = lm;              // mu used by S-update of iteration k
      P[16+k] = b3;
      P[20+k] = 1.f/(b3+r);
      float lmn = (b3*(-LOGD) - z1 + r*lm)/(b3+r);
      z1 += r*(expf(lmn)-expf(lm));
      lm = lmn;
    }
  }
}

// ---- K2: fused MLP via bf16 MFMA (unchanged structure) ----
#define LPW 72
__global__ __launch_bounds__(512, 2) void k_mlp(
    const float* __restrict__ x, const unsigned short* __restrict__ w1b,
    const float* __restrict__ W2, float* __restrict__ logits, int T)
{
  __shared__ unsigned short Xs[128*LPW];
  __shared__ unsigned short Ws[128*LPW];
  __shared__ float lred[128];
  const int by = blockIdx.x;
  const int bx = blockIdx.y;
  const int tid = threadIdx.x;
  if (tid < 128) lred[tid] = 0.f;

  const int l = tid & 63;
  const int w = tid >> 6;
  const int wm = w >> 2;
  const int wn = w & 3;
  const int lr = l & 15, quad = l >> 4;
  const int srow = tid >> 2;
  const int sseg = tid & 3;
  const int wrow = tid >> 3;
  const int wseg = tid & 7;

  f32x4 acc[4][2];
  #pragma unroll
  for (int mi=0;mi<4;mi++)
    #pragma unroll
    for (int ni=0;ni<2;ni++) acc[mi][ni] = (f32x4){0.f,0.f,0.f,0.f};

  for (int kt=0; kt<4; kt++){
    const int k0 = kt*64;
    {
      const int grow = bx*128 + srow;
      #pragma unroll
      for (int i=0;i<4;i++){
        float4 v = make_float4(0.f,0.f,0.f,0.f);
        if (grow < T) v = *(const float4*)(x + (size_t)grow*DD + k0 + sseg*16 + i*4);
        *(ushort4*)&Xs[srow*LPW + sseg*16 + i*4] =
            make_ushort4(f2bf(v.x), f2bf(v.y), f2bf(v.z), f2bf(v.w));
      }
    }
    #pragma unroll
    for (int h=0; h<2; h++){
      const int r = h*64 + wrow;
      *(short8*)&Ws[r*LPW + wseg*8] =
          *(const short8*)(w1b + (size_t)(by*128 + r)*DD + k0 + wseg*8);
    }
    __syncthreads();
    #pragma unroll
    for (int ks=0; ks<2; ks++){
      short8 afr[4], bfr[2];
      #pragma unroll
      for (int mi=0;mi<4;mi++)
        afr[mi] = *(const short8*)&Xs[(wm*64 + mi*16 + lr)*LPW + ks*32 + quad*8];
      #pragma unroll
      for (int ni=0;ni<2;ni++)
        bfr[ni] = *(const short8*)&Ws[(wn*32 + ni*16 + lr)*LPW + ks*32 + quad*8];
      #pragma unroll
      for (int mi=0;mi<4;mi++)
        #pragma unroll
        for (int ni=0;ni<2;ni++)
          acc[mi][ni] = __builtin_amdgcn_mfma_f32_16x16x32_bf16(afr[mi], bfr[ni], acc[mi][ni], 0, 0, 0);
    }
    __syncthreads();
  }

  float w2v[2];
  #pragma unroll
  for (int ni=0;ni<2;ni++) w2v[ni] = W2[by*128 + wn*32 + ni*16 + lr];
  #pragma unroll
  for (int mi=0;mi<4;mi++){
    float p[4];
    #pragma unroll
    for (int v=0; v<4; v++){
      p[v] = fast_tanh(acc[mi][0][v])*w2v[0] + fast_tanh(acc[mi][1][v])*w2v[1];
      #pragma unroll
      for (int off=1; off<16; off<<=1) p[v] += __shfl_xor(p[v], off, 64);
    }
    if (lr == 0){
      #pragma unroll
      for (int v=0; v<4; v++)
        atomicAdd(&lred[wm*64 + mi*16 + quad*4 + v], p[v]);
    }
  }
  __syncthreads();
  if (tid < 128){
    const int grow = bx*128 + tid;
    if (grow < T) atomicAdd(logits + grow, lred[tid]);
  }
}

// ---- K4: BADMM solver, round-4 restructure ----
// Evidence rounds 0-3: occupancy is pinned at 16 waves/CU regardless of
// strategy; kernel is latency-bound on the per-row 6-step wave reduction and
// the A-state LDS round trip. This round shortens the chain instead:
//  * A and z fully in REGISTERS (s16-packed, 32+32 VGPR). A was only ever
//    accessed by its owning thread -> LDS was pure register relief. LDS now
//    red(32x260 f32) + colv = ~34 KB.
//  * Lane remap: wave = 4 rows x 16 lanes x 16 cols (col = 4*c0 + 64q + j).
//    Row-sum = 4-step shfl_xor{1,2,4,8} reducing 4 rows AT ONCE: shuffle
//    instrs/sweep 96 -> 16, chain 6 -> 4 steps, per-lane redundant log/eta
//    recurrences 16 -> 4 per sweep.
//  * y encoded s16 pre-reduction; wave-uniform off added post-reduction via
//    v_pk_add_i16 clamp (saturation = old -63 clamp). Keeps fp32 y[16] out
//    of the live range -> fits 128 VGPR (512 thr, 4 waves/EU, 2 blocks/CU).
//  * x loads perfectly coalesced (16 lanes = 256B contiguous per row); red
//    stride 260 floats -> uniform bank spread; colv reads 2-way (free).
__global__ __launch_bounds__(512, 4) void k_solver(
    const float* __restrict__ x, const float* __restrict__ logits,
    const int* __restrict__ starts, const float* __restrict__ P,
    float* __restrict__ out)
{
  __shared__ __align__(16) float red[32*RST];   // 33280 B: column partials
  __shared__ __align__(16) float colv[DD];      // 1 KB: column log-sum
  const int b = blockIdx.x;
  const int start = starts[b];
  const int len = starts[b+1] - start;
  const int tid = threadIdx.x;
  const int w = tid >> 6, l = tid & 63;
  const int sub = l >> 4;          // row within 4-row group
  const int c0  = l & 15;          // column slice
  const int n0 = w*16;
  int nv = len - n0; nv = nv < 0 ? 0 : (nv > 16 ? 16 : nv);

  // scalar params (wave-uniform s_loads)
  const float r0=P[0], r1=P[1], r2=P[2], r3=P[3];
  const float i10=P[4], i11=P[5], i12=P[6];
  const float i20=P[8], i21=P[9], i22=P[10], i23=P[11];
  const float mu0=P[12], mu1=P[13], mu2=P[14];
  const float b30=P[16], b31=P[17], b32=P[18];
  const float e30=P[20], e31=P[21], e32=P[22];

  // ---- fused segment softmax (per-wave redundant) ----
  const float* lg = logits + start;
  float v0 = (l      < len) ? lg[l]    : -3.0e38f;
  float v1 = (l+64   < len) ? lg[l+64] : -3.0e38f;
  float sm = wave_max(fmaxf(v0,v1));
  float se0 = (l    < len) ? __expf(v0-sm) : 0.f;
  float se1 = (l+64 < len) ? __expf(v1-sm) : 0.f;
  float ssum0 = wave_sum(se0+se1);
  const float sinv = 1.f/(ssum0 + 1e-16f);
  const float esel = (n0 < 64) ? se0 : se1;   // rows n0..n0+15 on one side of 64

  // per-group (4 rows/wave-group) state, lane-redundant within 16-lane group
  float slqg[4], etag[4], z2g[4];
  uint2 ap[4][4];   // s16 log-state, [group][q]: 32 VGPR
  uint2 zp[4][4];   // s16 dual z:               32 VGPR
  #pragma unroll
  for (int g=0; g<4; g++){
    const int row = n0 + 4*g + sub;
    const float ev = __shfl(esel, row & 63, 64);
    const float lq = __logf(ev*sinv + 1e-8f);
    slqg[g] = lq; etag[g] = lq; z2g[g] = 0.f;
    #pragma unroll
    for (int q=0;q<4;q++){ zp[g][q].x = 0u; zp[g][q].y = 0u; }
  }

  const float* xbase = x + (size_t)(start + n0 + sub)*DD + 4*c0;

  // ================= sweep 0: T(0) + colsum for S(0) =================
  {
    float sp[16];
    #pragma unroll
    for (int j=0;j<16;j++) sp[j]=0.f;
    #pragma unroll
    for (int g=0; g<4; g++){
      if (4*g + sub < nv){
        const float* xp = xbase + (size_t)(4*g)*DD;
        const float a0 = slqg[g] - LOGD;
        float ss = 0.f;
        #pragma unroll
        for (int q=0;q<4;q++){
          const float4 xv = *(const float4*)(xp + 64*q);
          const float xvv[4] = {xv.x, xv.y, xv.z, xv.w};
          int ny[4];
          #pragma unroll
          for (int j=0;j<4;j++){
            const float y = (xvv[j] + r0*a0) * i20;
            ss += __expf(y);
            ny[j] = __float2int_rn(y*512.f);
          }
          ap[0][q] = ap[0][q]; // no-op placeholder removed by compiler
          ap[g][q].x = pk2(ny[0],ny[1]);
          ap[g][q].y = pk2(ny[2],ny[3]);
        }
        ss = grp_sum(ss);
        const float off = etag[g] - __logf(ss);
        const int offi = __float2int_rn(fmaxf(off, -56.f)*512.f);
        const unsigned offpk = pk2(offi, offi);
        #pragma unroll
        for (int q=0;q<4;q++){
          ap[g][q].x = pkadd_sat(ap[g][q].x, offpk);
          ap[g][q].y = pkadd_sat(ap[g][q].y, offpk);
          sp[4*q+0] += __expf((r0*decq(lo16(ap[g][q].x))) * i10);
          sp[4*q+1] += __expf((r0*decq(hi16(ap[g][q].x))) * i10);
          sp[4*q+2] += __expf((r0*decq(lo16(ap[g][q].y))) * i10);
          sp[4*q+3] += __expf((r0*decq(hi16(ap[g][q].y))) * i10);
        }
        const float en = (b30*slqg[g] - z2g[g] + r0*etag[g]) * e30;
        z2g[g] += r0*(__expf(en) - __expf(etag[g]));
        etag[g] = en;
      }
    }
    #pragma unroll
    for (int q=0;q<4;q++)
      *(float4*)&red[(4*w+sub)*RST + 64*q + 4*c0] =
          make_float4(sp[4*q], sp[4*q+1], sp[4*q+2], sp[4*q+3]);
  }
  __syncthreads();
  if (tid < DD){
    float s = 0.f;
    #pragma unroll
    for (int i=0;i<32;i++) s += red[i*RST + tid];
    colv[tid] = __logf(s);
  }
  __syncthreads();

  // ============ sweeps 1..2: S(k-1) + z + T(k) + colsum(k) ============
  #pragma unroll
  for (int k=1;k<3;k++){
    const float rkm = (k==1)? r0 : r1;
    const float ib1m= (k==1)? i10 : i11;
    const float mum = (k==1)? mu0 : mu1;
    const float rk  = (k==1)? r1 : r2;
    const float ib1k= (k==1)? i11 : i12;
    const float ib2k= (k==1)? i21 : i22;
    const float b3k = (k==1)? b31 : b32;
    const float e3k = (k==1)? e31 : e32;
    float sp[16];
    #pragma unroll
    for (int j=0;j<16;j++) sp[j]=0.f;
    #pragma unroll
    for (int g=0; g<4; g++){
      if (4*g + sub < nv){
        const float* xp = xbase + (size_t)(4*g)*DD;
        float ss = 0.f;
        #pragma unroll
        for (int q=0;q<4;q++){
          const float4 lscq = *(const float4*)&colv[64*q + 4*c0];
          const float4 xv   = *(const float4*)(xp + 64*q);
          const float xvv[4]  = {xv.x, xv.y, xv.z, xv.w};
          const float lscv[4] = {lscq.x, lscq.y, lscq.z, lscq.w};
          const int aq[4] = {lo16(ap[g][q].x), hi16(ap[g][q].x),
                             lo16(ap[g][q].y), hi16(ap[g][q].y)};
          const int zq[4] = {lo16(zp[g][q].x), hi16(zp[g][q].x),
                             lo16(zp[g][q].y), hi16(zp[g][q].y)};
          int ny[4], nz[4];
          #pragma unroll
          for (int j=0;j<4;j++){
            const float lt = decq(aq[j]);
            float zf = zdec(zq[j]);
            const float ys  = (zf + rkm*lt) * ib1m;
            const float lsn = mum + ys - lscv[j];
            zf += rkm*(__expf(lt) - __expf(lsn));
            nz[j] = zenc(zf);
            const float y = (xvv[j] - zdec(nz[j]) + rk*lsn) * ib2k;
            ss += __expf(y);
            ny[j] = __float2int_rn(y*512.f);
          }
          ap[g][q].x = pk2(ny[0],ny[1]);
          ap[g][q].y = pk2(ny[2],ny[3]);
          zp[g][q].x = pk2(nz[0],nz[1]);
          zp[g][q].y = pk2(nz[2],nz[3]);
        }
        ss = grp_sum(ss);
        const float off = etag[g] - __logf(ss);
        const int offi = __float2int_rn(fmaxf(off, -56.f)*512.f);
        const unsigned offpk = pk2(offi, offi);
        #pragma unroll
        for (int q=0;q<4;q++){
          ap[g][q].x = pkadd_sat(ap[g][q].x, offpk);
          ap[g][q].y = pkadd_sat(ap[g][q].y, offpk);
          sp[4*q+0] += __expf((zdec(lo16(zp[g][q].x)) + rk*decq(lo16(ap[g][q].x))) * ib1k);
          sp[4*q+1] += __expf((zdec(hi16(zp[g][q].x)) + rk*decq(hi16(ap[g][q].x))) * ib1k);
          sp[4*q+2] += __expf((zdec(lo16(zp[g][q].y)) + rk*decq(lo16(ap[g][q].y))) * ib1k);
          sp[4*q+3] += __expf((zdec(hi16(zp[g][q].y)) + rk*decq(hi16(ap[g][q].y))) * ib1k);
        }
        const float en = (b3k*slqg[g] - z2g[g] + rk*etag[g]) * e3k;
        z2g[g] += rk*(__expf(en) - __expf(etag[g]));
        etag[g] = en;
      }
    }
    #pragma unroll
    for (int q=0;q<4;q++)
      *(float4*)&red[(4*w+sub)*RST + 64*q + 4*c0] =
          make_float4(sp[4*q], sp[4*q+1], sp[4*q+2], sp[4*q+3]);
    __syncthreads();
    if (tid < DD){
      float s = 0.f;
      #pragma unroll
      for (int i=0;i<32;i++) s += red[i*RST + tid];
      colv[tid] = __logf(s);
    }
    __syncthreads();
  }

  // ============ sweep 3: S(2) + z + T(3) + output ============
  {
    float op[16];
    #pragma unroll
    for (int j=0;j<16;j++) op[j]=0.f;
    #pragma unroll
    for (int g=0; g<4; g++){
      if (4*g + sub < nv){
        const float* xp = xbase + (size_t)(4*g)*DD;
        float ey[16];
        float ss = 0.f;
        #pragma unroll
        for (int q=0;q<4;q++){
          const float4 lscq = *(const float4*)&colv[64*q + 4*c0];
          const float4 xv   = *(const float4*)(xp + 64*q);
          const float xvv[4]  = {xv.x, xv.y, xv.z, xv.w};
          const float lscv[4] = {lscq.x, lscq.y, lscq.z, lscq.w};
          const int aq[4] = {lo16(ap[g][q].x), hi16(ap[g][q].x),
                             lo16(ap[g][q].y), hi16(ap[g][q].y)};
          const int zq[4] = {lo16(zp[g][q].x), hi16(zp[g][q].x),
                             lo16(zp[g][q].y), hi16(zp[g][q].y)};
          #pragma unroll
          for (int j=0;j<4;j++){
            const float lt = decq(aq[j]);
            float zf = zdec(zq[j]);
            const float ys  = (zf + r2*lt) * i12;
            const float lsn = mu2 + ys - lscv[j];
            zf += r2*(__expf(lt) - __expf(lsn));
            const float y = (xvv[j] - zf + r3*lsn) * i23;
            const float e = __expf(y);
            ey[4*q+j] = e;
            ss += e;
          }
        }
        ss = grp_sum(ss);
        const float rs = __expf(etag[g]) / ss;   // t = ey * exp(eta3)/se
        #pragma unroll
        for (int q=0;q<4;q++){
          const float4 xv = *(const float4*)(xp + 64*q);   // L1-hot reload
          op[4*q+0] += xv.x * ey[4*q+0] * rs;
          op[4*q+1] += xv.y * ey[4*q+1] * rs;
          op[4*q+2] += xv.z * ey[4*q+2] * rs;
          op[4*q+3] += xv.w * ey[4*q+3] * rs;
        }
      }
    }
    #pragma unroll
    for (int q=0;q<4;q++)
      *(float4*)&red[(4*w+sub)*RST + 64*q + 4*c0] =
          make_float4(op[4*q], op[4*q+1], op[4*q+2], op[4*q+3]);
    __syncthreads();
    if (tid < DD){
      float s = 0.f;
      #pragma unroll
      for (int i=0;i<32;i++) s += red[i*RST + tid];
      out[(size_t)b*DD + tid] = 256.0f * s;
    }
  }
}

extern "C" void kernel_launch(void* const* d_in, const int* in_sizes, int n_in,
                              void* d_out, int out_size, void* d_ws, size_t ws_size,
                              hipStream_t stream) {
  const float* x    = (const float*)d_in[0];
  const int*   batch= (const int*)d_in[1];
  const float* W1   = (const float*)d_in[2];
  const float* W2   = (const float*)d_in[3];
  const float* rho  = (const float*)d_in[4];
  const float* a1   = (const float*)d_in[5];
  const float* a2   = (const float*)d_in[6];
  const float* a3   = (const float*)d_in[7];
  float* out = (float*)d_out;
  const int T = in_sizes[1];   // total ragged rows

  float* logits = (float*)d_ws;              // T floats
  int*   starts = (int*)(logits + T);        // B+1 ints (padded to 1028)
  float* P      = (float*)(starts + 1028);   // 24 floats (padded to 32)
  unsigned short* w1b = (unsigned short*)(P + 32);  // 512*256 bf16

  k_pre<<<70, 256, 0, stream>>>(W1, w1b, batch, T, starts, rho, a1, a2, a3, P);
  hipMemsetAsync(logits, 0, (size_t)T*sizeof(float), stream);
  k_mlp<<<dim3(4, (T+127)/128), 512, 0, stream>>>(x, w1b, W2, logits, T);
  k_solver<<<BB, 512, 0, stream>>>(x, logits, starts, P, out);
}